// Round 1
// baseline (181.361 us; speedup 1.0000x reference)
//
#include <hip/hip_runtime.h>
#include <hip/hip_bf16.h>
#include <stdint.h>

// y[c,k] = sum_{a,b} E1[k,a] * Xc[c,a,b] * E2[k,b],  Xc = C*x, E = exp(i*angle*g)
// Stage 1 (MFMA): tmp[a, 2k+comp] = A'[a,:] @ B'[:, 2k+comp]
//   A' = [Re(Xc) | Im(Xc)]  (256 x 512)
//   B'[b,2k]=Er, B'[256+b,2k]=-Ei, B'[b,2k+1]=Ei, B'[256+b,2k+1]=Er
// Stage 2 (epilogue): y[c,k] = sum_a E1[k,a] (*) tmp[a,k]  (complex), * w[k%512]

#define NKTOT 17408
#define NBLK_K 272   // 17408 / 64
#define LDA 512
#define LDBT 512

typedef short bf16x8 __attribute__((ext_vector_type(8)));
typedef float f32x4 __attribute__((ext_vector_type(4)));

__device__ __forceinline__ unsigned short f2bf(float f) {
  unsigned int u = __builtin_bit_cast(unsigned int, f);
  u += 0x7FFFu + ((u >> 16) & 1u);
  return (unsigned short)(u >> 16);
}
__device__ __forceinline__ float bf2f(unsigned int lo16) {
  return __builtin_bit_cast(float, lo16 << 16);
}

__device__ __forceinline__ void async_copy16(void* lds, const void* g) {
  __builtin_amdgcn_global_load_lds(
      (const __attribute__((address_space(1))) unsigned int*)g,
      (__attribute__((address_space(3))) unsigned int*)lds, 16, 0, 0);
}

__global__ __launch_bounds__(256) void pack_a(
    const float* __restrict__ input_r, const float* __restrict__ C_r,
    unsigned short* __restrict__ Apack)
{
  int tid = blockIdx.x * 256 + threadIdx.x;  // 0 .. 8*256*256-1
  int b = tid & 255;
  int a = (tid >> 8) & 255;
  int c = tid >> 16;
  float xr = input_r[(a * 256 + b) * 2 + 0];
  float xi = input_r[(a * 256 + b) * 2 + 1];
  size_t ci0 = ((size_t)(c * 256 + a) * 256 + b) * 2;
  float cr = C_r[ci0 + 0];
  float ci = C_r[ci0 + 1];
  float re = cr * xr - ci * xi;
  float im = cr * xi + ci * xr;
  size_t base = (size_t)c * (256 * LDA) + (size_t)a * LDA;
  Apack[base + b] = f2bf(re);
  Apack[base + 256 + b] = f2bf(im);
}

__global__ __launch_bounds__(256) void pack_be(
    const float* __restrict__ angle,
    unsigned short* __restrict__ BT, unsigned int* __restrict__ E1tab)
{
  int k = blockIdx.x;    // 0..17407
  int b = threadIdx.x;   // 0..255
  float s = angle[k * 2 + 0];
  float t = angle[k * 2 + 1];
  float g = (float)(b - 128);
  float e2s, e2c, e1s, e1c;
  __sincosf(t * g, &e2s, &e2c);
  __sincosf(s * g, &e1s, &e1c);
  size_t r0 = (size_t)(2 * k) * LDBT;
  BT[r0 + b]               = f2bf(e2c);
  BT[r0 + 256 + b]         = f2bf(-e2s);
  BT[r0 + LDBT + b]        = f2bf(e2s);
  BT[r0 + LDBT + 256 + b]  = f2bf(e2c);
  E1tab[k * 256 + b] = (unsigned int)f2bf(e1c) | ((unsigned int)f2bf(e1s) << 16);
}

__global__ __launch_bounds__(256, 2) void gemm_fused(
    const unsigned short* __restrict__ Apack,
    const unsigned short* __restrict__ BT,
    const unsigned int* __restrict__ E1tab,
    const float* __restrict__ wvec,
    float* __restrict__ out)
{
  __shared__ unsigned short As[256 * 64];  // 32 KB, row a x col kb (pitch 64)
  __shared__ unsigned short Bs[128 * 64];  // 16 KB, row n x col kb (pitch 64)
  __shared__ float wavecol[4][128];

  const int bx = blockIdx.x;
  const int c = bx / NBLK_K;
  const int kt0 = (bx % NBLK_K) * 64;
  const int tid = threadIdx.x;
  const int w = tid >> 6;
  const int l = tid & 63;
  const int lhi = l >> 4;   // 0..3
  const int llo = l & 15;
  const int lr = l >> 3;        // staging: row within 8-row chunk
  const int lc = (l & 7) * 8;   // staging: col offset (8 bf16 = 16B)

  const unsigned short* Abase = Apack + (size_t)c * (256 * LDA);
  const unsigned short* Bbase = BT + (size_t)(kt0 * 2) * LDBT;

  f32x4 acc[4][8];
#pragma unroll
  for (int i = 0; i < 4; ++i)
#pragma unroll
    for (int j = 0; j < 8; ++j) {
      f32x4 z = {0.f, 0.f, 0.f, 0.f};
      acc[i][j] = z;
    }

  for (int kk = 0; kk < 512; kk += 64) {
    // stage A tile: 256x64 bf16 = 32 chunks of 1KB (8 rows each); wave w does 8
#pragma unroll
    for (int i = 0; i < 8; ++i) {
      int row0 = (w * 8 + i) * 8;
      async_copy16(&As[row0 * 64], Abase + (size_t)(row0 + lr) * LDA + kk + lc);
    }
    // stage B tile: 128x64 bf16 = 16 chunks; wave w does 4
#pragma unroll
    for (int i = 0; i < 4; ++i) {
      int row0 = (w * 4 + i) * 8;
      async_copy16(&Bs[row0 * 64], Bbase + (size_t)(row0 + lr) * LDBT + kk + lc);
    }
    __syncthreads();
#pragma unroll
    for (int kf = 0; kf < 2; ++kf) {
      const int colb = kf * 32 + lhi * 8;
      bf16x8 af[4];
      bf16x8 bfr[8];
#pragma unroll
      for (int fi = 0; fi < 4; ++fi)
        af[fi] = *(const bf16x8*)&As[(w * 64 + fi * 16 + llo) * 64 + colb];
#pragma unroll
      for (int fj = 0; fj < 8; ++fj)
        bfr[fj] = *(const bf16x8*)&Bs[(fj * 16 + llo) * 64 + colb];
#pragma unroll
      for (int fi = 0; fi < 4; ++fi)
#pragma unroll
        for (int fj = 0; fj < 8; ++fj)
          acc[fi][fj] = __builtin_amdgcn_mfma_f32_16x16x32_bf16(
              af[fi], bfr[fj], acc[fi][fj], 0, 0, 0);
    }
    __syncthreads();
  }

  // Epilogue: y_partial[col] = sum over this wave's a-rows of E1 (*) tmp
  // col = fj*16 + llo; even col -> Re(tmp), odd -> Im(tmp) for k = kt0 + col/2
#pragma unroll
  for (int fj = 0; fj < 8; ++fj) {
    const int col = fj * 16 + llo;
    const int k = kt0 + (col >> 1);
    const float sign = (col & 1) ? 1.f : -1.f;
    float sum = 0.f;
    const unsigned int* e1base = E1tab + (size_t)k * 256 + w * 64 + lhi * 4;
#pragma unroll
    for (int fi = 0; fi < 4; ++fi) {
      uint4 e4 = *(const uint4*)(e1base + fi * 16);
      unsigned int ev[4] = {e4.x, e4.y, e4.z, e4.w};
#pragma unroll
      for (int r = 0; r < 4; ++r) {
        float v = acc[fi][fj][r];             // this comp at (a, k)
        float p = __shfl_xor(v, 1, 64);       // partner comp at same (a, k)
        float er = bf2f(ev[r] & 0xFFFFu);
        float ei = bf2f(ev[r] >> 16);
        // even col: Re(y) += er*tr - ei*ti ; odd col: Im(y) += er*ti + ei*tr
        sum += er * v + sign * ei * p;
      }
    }
    sum += __shfl_xor(sum, 16, 64);
    sum += __shfl_xor(sum, 32, 64);
    if (lhi == 0) wavecol[w][col] = sum;
  }
  __syncthreads();
  if (tid < 128) {
    float sv = wavecol[0][tid] + wavecol[1][tid] + wavecol[2][tid] + wavecol[3][tid];
    int k = kt0 + (tid >> 1);
    out[((size_t)c * NKTOT + k) * 2 + (tid & 1)] = sv * wvec[k & 511];
  }
}

extern "C" void kernel_launch(void* const* d_in, const int* in_sizes, int n_in,
                              void* d_out, int out_size, void* d_ws, size_t ws_size,
                              hipStream_t stream) {
  const float* input_r = (const float*)d_in[0];  // (256,256,2)
  const float* C_r     = (const float*)d_in[1];  // (8,256,256,2)
  const float* wvec    = (const float*)d_in[2];  // (512,)
  const float* angle   = (const float*)d_in[3];  // (17408,2)
  float* out = (float*)d_out;                    // (8,17408,2)

  // workspace layout: A' (2MB) | B'T (34MB) | E1tab (17MB)  => ~53MB
  unsigned short* Apack = (unsigned short*)d_ws;
  unsigned short* BT    = (unsigned short*)((char*)d_ws + (size_t)2097152);
  unsigned int*   E1tab = (unsigned int*)((char*)d_ws + (size_t)2097152 + 35651584);

  pack_a<<<2048, 256, 0, stream>>>(input_r, C_r, Apack);
  pack_be<<<NKTOT, 256, 0, stream>>>(angle, BT, E1tab);
  gemm_fused<<<8 * NBLK_K, 256, 0, stream>>>(Apack, BT, E1tab, wvec, out);
}

// Round 2
// 159.329 us; speedup vs baseline: 1.1383x; 1.1383x over previous
//
#include <hip/hip_runtime.h>
#include <hip/hip_bf16.h>
#include <stdint.h>

// y[c,k] = sum_{a,b} E1[k,a] * Xc[c,a,b] * E2[k,b],  Xc = C*x, E = exp(i*angle*g)
// Stage 1 (MFMA): tmp[a, 2k+comp] = A'[a,:] @ B'[:, 2k+comp]
//   A' = [Re(Xc) | Im(Xc)]  (256 x 512)
//   B'[b,2k]=Er, B'[256+b,2k]=-Ei, B'[b,2k+1]=Ei, B'[256+b,2k+1]=Er
// Stage 2 (epilogue): y[c,k] = sum_a E1[k,a] (*) tmp[a,k]  (complex), * w[k%512]
//
// LDS tiles use a chunk-XOR swizzle (slot = chunk ^ (row&7)) so fragment
// ds_read_b128s are perfectly bank-balanced (pitch 128B == 32 banks would
// otherwise put every row at bank 0 -> 4x read serialization, the 2e7
// SQ_LDS_BANK_CONFLICT seen in R1). Staging via global_load_lds keeps
// dest = base + lane*16; only the per-lane global source chunk is permuted.

#define NKTOT 17408
#define NBLK_K 272   // 17408 / 64
#define LDA 512
#define LDBT 512

typedef short bf16x8 __attribute__((ext_vector_type(8)));
typedef float f32x4 __attribute__((ext_vector_type(4)));

__device__ __forceinline__ unsigned short f2bf(float f) {
  unsigned int u = __builtin_bit_cast(unsigned int, f);
  u += 0x7FFFu + ((u >> 16) & 1u);
  return (unsigned short)(u >> 16);
}
__device__ __forceinline__ float bf2f(unsigned int lo16) {
  return __builtin_bit_cast(float, lo16 << 16);
}

__device__ __forceinline__ void async_copy16(void* lds, const void* g) {
  __builtin_amdgcn_global_load_lds(
      (const __attribute__((address_space(1))) unsigned int*)g,
      (__attribute__((address_space(3))) unsigned int*)lds, 16, 0, 0);
}

__global__ __launch_bounds__(256) void pack_a(
    const float* __restrict__ input_r, const float* __restrict__ C_r,
    unsigned short* __restrict__ Apack)
{
  int tid = blockIdx.x * 256 + threadIdx.x;  // 0 .. 8*256*256-1
  int b = tid & 255;
  int a = (tid >> 8) & 255;
  int c = tid >> 16;
  float xr = input_r[(a * 256 + b) * 2 + 0];
  float xi = input_r[(a * 256 + b) * 2 + 1];
  size_t ci0 = ((size_t)(c * 256 + a) * 256 + b) * 2;
  float cr = C_r[ci0 + 0];
  float ci = C_r[ci0 + 1];
  float re = cr * xr - ci * xi;
  float im = cr * xi + ci * xr;
  size_t base = (size_t)c * (256 * LDA) + (size_t)a * LDA;
  Apack[base + b] = f2bf(re);
  Apack[base + 256 + b] = f2bf(im);
}

__global__ __launch_bounds__(256) void pack_be(
    const float* __restrict__ angle,
    unsigned short* __restrict__ BT, unsigned int* __restrict__ E1tab)
{
  int k = blockIdx.x;    // 0..17407
  int b = threadIdx.x;   // 0..255
  float s = angle[k * 2 + 0];
  float t = angle[k * 2 + 1];
  float g = (float)(b - 128);
  float e2s, e2c, e1s, e1c;
  __sincosf(t * g, &e2s, &e2c);
  __sincosf(s * g, &e1s, &e1c);
  size_t r0 = (size_t)(2 * k) * LDBT;
  BT[r0 + b]               = f2bf(e2c);
  BT[r0 + 256 + b]         = f2bf(-e2s);
  BT[r0 + LDBT + b]        = f2bf(e2s);
  BT[r0 + LDBT + 256 + b]  = f2bf(e2c);
  E1tab[k * 256 + b] = (unsigned int)f2bf(e1c) | ((unsigned int)f2bf(e1s) << 16);
}

__global__ __launch_bounds__(256, 2) void gemm_fused(
    const unsigned short* __restrict__ Apack,
    const unsigned short* __restrict__ BT,
    const unsigned int* __restrict__ E1tab,
    const float* __restrict__ wvec,
    float* __restrict__ out)
{
  __shared__ unsigned short As[256 * 64];  // 32 KB, row a x 8 swizzled 16B slots
  __shared__ unsigned short Bs[128 * 64];  // 16 KB
  __shared__ float wavecol[4][128];

  // XCD-aware decode: bx = ktHigh*64 + c*8 + (kt&7); bx%8 == kt%8 keeps all
  // 8 c-blocks of one kt on the same XCD so its L2 serves B/E1 tiles once.
  const int bx = blockIdx.x;
  const int c = (bx >> 3) & 7;
  const int kt = (bx >> 6) * 8 + (bx & 7);
  const int kt0 = kt * 64;
  const int tid = threadIdx.x;
  const int w = tid >> 6;
  const int l = tid & 63;
  const int lhi = l >> 4;   // 0..3
  const int llo = l & 15;
  const int lr = l >> 3;                       // staging: row within 8-row chunk
  const int lcs = ((l & 7) ^ (l >> 3)) * 8;    // staging: swizzled source chunk

  const unsigned short* Abase = Apack + (size_t)c * (256 * LDA);
  const unsigned short* Bbase = BT + (size_t)(kt0 * 2) * LDBT;

  f32x4 acc[4][8];
#pragma unroll
  for (int i = 0; i < 4; ++i)
#pragma unroll
    for (int j = 0; j < 8; ++j) {
      f32x4 z = {0.f, 0.f, 0.f, 0.f};
      acc[i][j] = z;
    }

  for (int kk = 0; kk < 512; kk += 64) {
    // stage A tile: 256x64 bf16 = 32 chunks of 1KB (8 rows each); wave w does 8
#pragma unroll
    for (int i = 0; i < 8; ++i) {
      int row0 = (w * 8 + i) * 8;
      async_copy16(&As[row0 * 64], Abase + (size_t)(row0 + lr) * LDA + kk + lcs);
    }
    // stage B tile: 128x64 bf16 = 16 chunks; wave w does 4
#pragma unroll
    for (int i = 0; i < 4; ++i) {
      int row0 = (w * 4 + i) * 8;
      async_copy16(&Bs[row0 * 64], Bbase + (size_t)(row0 + lr) * LDBT + kk + lcs);
    }
    __syncthreads();
#pragma unroll
    for (int kf = 0; kf < 2; ++kf) {
      const int slotbase = kf * 4 + lhi;
      const int soff = (slotbase ^ (llo & 7)) * 8;  // swizzled chunk -> elem off
      bf16x8 af[4];
      bf16x8 bfr[8];
#pragma unroll
      for (int fi = 0; fi < 4; ++fi)
        af[fi] = *(const bf16x8*)&As[(w * 64 + fi * 16 + llo) * 64 + soff];
#pragma unroll
      for (int fj = 0; fj < 8; ++fj)
        bfr[fj] = *(const bf16x8*)&Bs[(fj * 16 + llo) * 64 + soff];
#pragma unroll
      for (int fi = 0; fi < 4; ++fi)
#pragma unroll
        for (int fj = 0; fj < 8; ++fj)
          acc[fi][fj] = __builtin_amdgcn_mfma_f32_16x16x32_bf16(
              af[fi], bfr[fj], acc[fi][fj], 0, 0, 0);
    }
    __syncthreads();
  }

  // Epilogue: y_partial[col] = sum over this wave's a-rows of E1 (*) tmp
  // col = fj*16 + llo; even col -> Re(tmp), odd -> Im(tmp) for k = kt0 + col/2
#pragma unroll
  for (int fj = 0; fj < 8; ++fj) {
    const int col = fj * 16 + llo;
    const int k = kt0 + (col >> 1);
    const float sign = (col & 1) ? 1.f : -1.f;
    float sum = 0.f;
    const unsigned int* e1base = E1tab + (size_t)k * 256 + w * 64 + lhi * 4;
#pragma unroll
    for (int fi = 0; fi < 4; ++fi) {
      uint4 e4 = *(const uint4*)(e1base + fi * 16);
      unsigned int ev[4] = {e4.x, e4.y, e4.z, e4.w};
#pragma unroll
      for (int r = 0; r < 4; ++r) {
        float v = acc[fi][fj][r];             // this comp at (a, k)
        float p = __shfl_xor(v, 1, 64);       // partner comp at same (a, k)
        float er = bf2f(ev[r] & 0xFFFFu);
        float ei = bf2f(ev[r] >> 16);
        // even col: Re(y) += er*tr - ei*ti ; odd col: Im(y) += er*ti + ei*tr
        sum += er * v + sign * ei * p;
      }
    }
    sum += __shfl_xor(sum, 16, 64);
    sum += __shfl_xor(sum, 32, 64);
    if (lhi == 0) wavecol[w][col] = sum;
  }
  __syncthreads();
  if (tid < 128) {
    float sv = wavecol[0][tid] + wavecol[1][tid] + wavecol[2][tid] + wavecol[3][tid];
    int k = kt0 + (tid >> 1);
    out[((size_t)c * NKTOT + k) * 2 + (tid & 1)] = sv * wvec[k & 511];
  }
}

extern "C" void kernel_launch(void* const* d_in, const int* in_sizes, int n_in,
                              void* d_out, int out_size, void* d_ws, size_t ws_size,
                              hipStream_t stream) {
  const float* input_r = (const float*)d_in[0];  // (256,256,2)
  const float* C_r     = (const float*)d_in[1];  // (8,256,256,2)
  const float* wvec    = (const float*)d_in[2];  // (512,)
  const float* angle   = (const float*)d_in[3];  // (17408,2)
  float* out = (float*)d_out;                    // (8,17408,2)

  // workspace layout: A' (2MB) | B'T (34MB) | E1tab (17MB)  => ~53MB
  unsigned short* Apack = (unsigned short*)d_ws;
  unsigned short* BT    = (unsigned short*)((char*)d_ws + (size_t)2097152);
  unsigned int*   E1tab = (unsigned int*)((char*)d_ws + (size_t)2097152 + 35651584);

  pack_a<<<2048, 256, 0, stream>>>(input_r, C_r, Apack);
  pack_be<<<NKTOT, 256, 0, stream>>>(angle, BT, E1tab);
  gemm_fused<<<8 * NBLK_K, 256, 0, stream>>>(Apack, BT, E1tab, wvec, out);
}